// Round 12
// baseline (728.366 us; speedup 1.0000x reference)
//
#include <hip/hip_runtime.h>
#include <hip/hip_fp16.h>

// LSTM B=256,T=512,IN=64,H=128,L=2 + FC.
// (Resubmission of R11: bench infra failed twice with no kernel verdict —
// same signature as R5, which passed on identical resubmission. Kernel
// re-audited: uniform barriers, legal 1024-thr block, 139KB LDS, h1-ring
// handoff correct, prefetch OOB lands in ws slack. Identical code.)
//
//  K0 cvt  : w_ih0 -> fp16 (tiny)
//  KG      : xg0 = x(f32).Wih0^T + bias -> [B*T][unit][4g] f16 (fused cvt)
//  KF      : layer-specialized 16-wave recurrence + chunked xg1 GEMM + FC
//
// R11: TLP instead of ILP. R8-R10 showed MfmaUtil+VALUBusy SUM (~89%) at
// 2 waves/SIMD: with both waves barrier-locked in the same phase, no wave
// exists to issue VALU while the MFMA pipe drains, and 3 scheduling
// attempts (stagger, SGB interleave) were null. Fix: 1024 threads = 16
// waves = 4/SIMD (LDS already forces 1 block/CU). Waves 0-7 run the
// L0 recurrence + the chunk xg-phase; waves 8-15 run the L1 recurrence
// (one chunk behind, act in-step). Per-wave state halves (ONE weight set
// B[4][4] selected by wave role, one acc, one cst) -> ~120 regs <= the
// 128-reg budget 4 waves/SIMD implies. Each SIMD hosts 2 L0 + 2 L1 waves:
// MFMA bursts and act-VALU overlap across waves (m114 mechanism).
// Structure per chunk k (65 chunks, CH=8): 8 steps (1 barrier each):
//   L0-wave (k<NCH): gates0(k*8+j) = h0(j-1) @ Whh0^T + xg0 (prefetched)
//   L1-wave:         gates1((k-1)*8+j) = h1(prev) @ Whh1^T + xg1t[j]
// then xg-phase on L0-waves: xg1t <- h0tile @ Wih1^T + b1 (w1lds 128KB,
// chunk-XOR swizzled) + 1 barrier. k=0: L1 zero-dynamics (zeroed xg1t/h1).
// Broadcast-row MFMA: all 16 A-rows = h; lane holds its unit's gate quad
// in a[g][0]; a[g][1..3] permanently stale.

#define TT 512
#define CH 8
#define NCH 64            // TT / CH
#define MM (256 * 512)
#define HP 136            // padded h0tile row stride

typedef _Float16 f16x4 __attribute__((ext_vector_type(4)));
typedef _Float16 f16x8 __attribute__((ext_vector_type(8)));
typedef float f32x4 __attribute__((ext_vector_type(4)));

__device__ __forceinline__ void bar_lgkm() {
    asm volatile("s_waitcnt lgkmcnt(0)" ::: "memory");
    __builtin_amdgcn_s_barrier();
}

__device__ __forceinline__ float tanh_f(float x) {
    float e = __expf(2.0f * x);
    return 1.0f - 2.0f * __builtin_amdgcn_rcpf(e + 1.0f);
}
__device__ __forceinline__ float sigm_f(float x) {
    return __builtin_amdgcn_rcpf(1.0f + __expf(-x));
}
__device__ __forceinline__ f16x8 cvt8(float4 a, float4 b) {
    f16x8 f;
    f[0] = (_Float16)a.x; f[1] = (_Float16)a.y;
    f[2] = (_Float16)a.z; f[3] = (_Float16)a.w;
    f[4] = (_Float16)b.x; f[5] = (_Float16)b.y;
    f[6] = (_Float16)b.z; f[7] = (_Float16)b.w;
    return f;
}

// ---------------- K0: fp32 -> fp16 cvt (vector4) ----------------
__global__ void cvt_f32_f16(const float* __restrict__ src,
                            _Float16* __restrict__ dst, int n4) {
    int i = blockIdx.x * blockDim.x + threadIdx.x;
    int stride = gridDim.x * blockDim.x;
    for (; i < n4; i += stride) {
        float4 v = ((const float4*)src)[i];
        f16x4 a;
        a[0] = (_Float16)v.x; a[1] = (_Float16)v.y;
        a[2] = (_Float16)v.z; a[3] = (_Float16)v.w;
        ((f16x4*)dst)[i] = a;
    }
}

// ------- KG: xg[M][u][4g] = A32[M,64] . W[512,64]^T + (bih+bhh) ----------
__global__ __launch_bounds__(256, 1) void gemm_xg0(
    const float* __restrict__ A32, const _Float16* __restrict__ W,
    const float* __restrict__ bih, const float* __restrict__ bhh,
    _Float16* __restrict__ out)
{
    const int l  = threadIdx.x & 63;
    const int w  = threadIdx.x >> 6;
    const int mb = blockIdx.x * 64 + w * 16;
    const int c  = l & 15;
    const int q  = l >> 4;

    __shared__ float biasl[512];
    for (int i = threadIdx.x; i < 512; i += 256) biasl[i] = bih[i] + bhh[i];
    __syncthreads();

    f32x4 C[32];
    #pragma unroll
    for (int i = 0; i < 32; ++i) C[i] = (f32x4){0.f, 0.f, 0.f, 0.f};

    #pragma unroll
    for (int ks = 0; ks < 2; ++ks) {
        const float* ap = A32 + (size_t)(mb + c) * 64 + ks * 32 + q * 8;
        f16x8 Af = cvt8(((const float4*)ap)[0], ((const float4*)ap)[1]);
        #pragma unroll
        for (int nt = 0; nt < 32; ++nt) {
            f16x8 Bf = *(const f16x8*)(W + (size_t)(nt * 16 + c) * 64 + ks * 32 + q * 8);
            C[nt] = __builtin_amdgcn_mfma_f32_16x16x32_f16(Af, Bf, C[nt], 0, 0, 0);
        }
    }
    #pragma unroll
    for (int uu = 0; uu < 8; ++uu) {
        float b0 = biasl[uu * 16 + c];
        float b1 = biasl[128 + uu * 16 + c];
        float b2 = biasl[256 + uu * 16 + c];
        float b3 = biasl[384 + uu * 16 + c];
        #pragma unroll
        for (int i = 0; i < 4; ++i) {
            int row = mb + q * 4 + i;
            f16x4 pk;
            pk[0] = (_Float16)(C[uu][i]      + b0);
            pk[1] = (_Float16)(C[8 + uu][i]  + b1);
            pk[2] = (_Float16)(C[16 + uu][i] + b2);
            pk[3] = (_Float16)(C[24 + uu][i] + b3);
            ((f16x4*)out)[(size_t)row * 128 + uu * 16 + c] = pk;
        }
    }
}

// ---------------- KF: 16-wave layer-specialized recurrence ----------------
__global__ __launch_bounds__(1024) void lstm_fused(
    const float* __restrict__ whh0, const float* __restrict__ wih1,
    const float* __restrict__ whh1,
    const float* __restrict__ bih1, const float* __restrict__ bhh1,
    const _Float16* __restrict__ xg0,   // [B*T][unit][4g] fp16 (bias incl.)
    const float* __restrict__ fc_w, const float* __restrict__ fc_b,
    float* __restrict__ out)
{
    const int t = threadIdx.x;
    const int b = blockIdx.x;
    const int wid = t >> 6;          // 0..15
    const int l = t & 63;
    const int q = l >> 4;            // quad 0..3
    const int c = l & 15;
    const bool isL1 = wid >= 8;
    const int unit = ((wid & 7) << 4) + c;   // 0..127

    __shared__ __align__(16) _Float16 w1lds[512 * 128];   // 128 KB
    __shared__ __align__(16) _Float16 xg1t[CH * 512];     //   8 KB
    __shared__ __align__(16) _Float16 h0tile[CH * HP];    // 2176 B
    __shared__ __align__(16) _Float16 h1buf[2][128];      //  512 B
    __shared__ float redbuf[128];                         //  512 B

    // ---- stage Wih1 -> LDS (half row per thread, cvt + chunk swizzle) ----
    {
        const int r = t >> 1;
        const int jb = (t & 1) << 3;
        const float4* src = (const float4*)(wih1 + (size_t)r * 128);
        #pragma unroll
        for (int j2 = 0; j2 < 8; ++j2) {
            const int j = jb + j2;
            *(f16x8*)&w1lds[r * 128 + ((j ^ (r & 7)) << 3)] =
                cvt8(src[2 * j], src[2 * j + 1]);
        }
    }

    // ---- resident B-frags for THIS wave's layer (64 VGPRs) ----
    const float* whh = isL1 ? whh1 : whh0;
    f16x8 B[4][4];
    #pragma unroll
    for (int g = 0; g < 4; ++g) {
        #pragma unroll
        for (int kt = 0; kt < 4; ++kt) {
            const size_t off = (size_t)((g << 7) + unit) * 128 + (kt << 5) + (q << 3);
            B[g][kt] = cvt8(((const float4*)(whh + off))[0],
                            ((const float4*)(whh + off))[1]);
        }
    }
    // xg-phase bias (L0-waves run the phase)
    float bias1g[4];
    if (!isL1) {
        #pragma unroll
        for (int g = 0; g < 4; ++g)
            bias1g[g] = bih1[(g << 7) + unit] + bhh1[(g << 7) + unit];
    }

    // zeros: xg1t (k=0 L1 zero-dynamics), h1buf both, h0 ring slot CH-1.
    if (t < 512) ((float4*)xg1t)[t] = make_float4(0.f, 0.f, 0.f, 0.f);
    if (t < 128) {
        h1buf[0][t] = (_Float16)0.f;
        h1buf[1][t] = (_Float16)0.f;
        h0tile[(CH - 1) * HP + t] = (_Float16)0.f;
    }

    // xg0 rotating prefetch (L0-waves only; depth 2, compile-time indexed).
    const f16x4* __restrict__ xgp = (const f16x4*)xg0 + (size_t)b * TT * 128 + unit;
    f16x4 xr[4];
    if (!isL1) {
        xr[0] = xgp[0];
        xr[1] = xgp[128];
        xr[2] = xr[0]; xr[3] = xr[0];   // overwritten before first use
    }

    // persistent accumulator; only [0] ever read (stale-lane trick).
    f32x4 a[4];
    #pragma unroll
    for (int g = 0; g < 4; ++g) a[g] = (f32x4){0.f, 0.f, 0.f, 0.f};
    float cst = 0.f;
    __syncthreads();

    #pragma unroll 1
    for (int k = 0; k <= NCH; ++k) {
        #pragma unroll
        for (int j = 0; j < CH; ++j) {
            const int rp = (j + CH - 1) & (CH - 1);
            if (isL1 || (k < NCH)) {
                // C-in: L0 from prefetched xg0 regs, L1 from xg1t LDS.
                f16x4 xv;
                if (isL1) xv = *(const f16x4*)&xg1t[(j << 9) + (unit << 2)];
                else      xv = xr[j & 3];
                #pragma unroll
                for (int g = 0; g < 4; ++g) a[g][0] = (float)xv[g];
                if (!isL1)   // prefetch step s+2 (spans barriers; ws slack)
                    xr[(j + 2) & 3] = xgp[(size_t)(k * CH + j + 2) * 128];

                // A-frags: broadcast rows of this layer's h (wave-uniform sel)
                const _Float16* hp = isL1 ? &h1buf[(j & 1) ^ 1][0]
                                          : &h0tile[rp * HP];
                #pragma unroll
                for (int kt = 0; kt < 4; ++kt) {
                    f16x8 Af = *(const f16x8*)&hp[(kt << 5) + (q << 3)];
                    #pragma unroll
                    for (int g = 0; g < 4; ++g)
                        a[g] = __builtin_amdgcn_mfma_f32_16x16x32_f16(Af, B[g][kt], a[g], 0, 0, 0);
                }
                // activation (L1 at k=0: exact zero-dynamics, stays 0)
                float gi = sigm_f(a[0][0]);
                float gf = sigm_f(a[1][0]);
                float gg = tanh_f(a[2][0]);
                float go = sigm_f(a[3][0]);
                cst = gf * cst + gi * gg;
                float hh = go * tanh_f(cst);
                if (l < 16) {
                    _Float16* wp = isL1 ? &h1buf[j & 1][unit]
                                        : &h0tile[j * HP + unit];
                    *wp = (_Float16)hh;
                    if (isL1 && k == NCH && j == CH - 1) redbuf[unit] = hh;
                }
            }
            bar_lgkm();   // h0(j)/h1(j) visible; vm loads stay in flight
        }

        // ---- xg-phase (L0-waves): xg1t = h0tile(chunk k) @ Wih1^T + b1 ----
        if (k < NCH) {
            if (!isL1) {
                f32x4 G[4];
                #pragma unroll
                for (int g = 0; g < 4; ++g)
                    G[g] = (f32x4){bias1g[g], bias1g[g], bias1g[g], bias1g[g]};
                #pragma unroll
                for (int kt = 0; kt < 4; ++kt) {
                    f16x8 Ah = *(const f16x8*)&h0tile[(c & 7) * HP + (kt << 5) + (q << 3)];
                    #pragma unroll
                    for (int g = 0; g < 4; ++g) {
                        f16x8 Bg = *(const f16x8*)&w1lds[(((g << 7) + unit) << 7) +
                                       ((((kt << 2) + q) ^ (c & 7)) << 3)];
                        G[g] = __builtin_amdgcn_mfma_f32_16x16x32_f16(Ah, Bg, G[g], 0, 0, 0);
                    }
                }
                #pragma unroll
                for (int i2 = 0; i2 < 4; ++i2) {   // D rows 8..15 dup rows 0..7
                    f16x4 pk;
                    pk[0] = (_Float16)G[0][i2]; pk[1] = (_Float16)G[1][i2];
                    pk[2] = (_Float16)G[2][i2]; pk[3] = (_Float16)G[3][i2];
                    *(f16x4*)&xg1t[((((q << 2) + i2) & 7) << 9) + (unit << 2)] = pk;
                }
            }
            bar_lgkm();
        }
    }

    // fused FC on h1(T-1) (redbuf written before the last in-loop barrier)
    if (t < 64) {
        float p = redbuf[t] * fc_w[t] + redbuf[t + 64] * fc_w[t + 64];
        #pragma unroll
        for (int off = 32; off > 0; off >>= 1) p += __shfl_down(p, off, 64);
        if (t == 0) out[b] = p + fc_b[0];
    }
}

extern "C" void kernel_launch(void* const* d_in, const int* in_sizes, int n_in,
                              void* d_out, int out_size, void* d_ws, size_t ws_size,
                              hipStream_t stream) {
    const float* x     = (const float*)d_in[0];
    const float* w_ih0 = (const float*)d_in[1];
    const float* w_hh0 = (const float*)d_in[2];
    const float* b_ih0 = (const float*)d_in[3];
    const float* b_hh0 = (const float*)d_in[4];
    const float* w_ih1 = (const float*)d_in[5];
    const float* w_hh1 = (const float*)d_in[6];
    const float* b_ih1 = (const float*)d_in[7];
    const float* b_hh1 = (const float*)d_in[8];
    const float* fc_w  = (const float*)d_in[9];
    const float* fc_b  = (const float*)d_in[10];
    float* out = (float*)d_out;

    // ws layout: xg [134217728] + 64KB prefetch slack + w0_16 [65536]
    char* ws = (char*)d_ws;
    _Float16* xg    = (_Float16*)(ws);
    _Float16* w0_16 = (_Float16*)(ws + 134217728 + 65536);

    cvt_f32_f16<<<dim3(32), dim3(256), 0, stream>>>(w_ih0, w0_16, (512 * 64) / 4);

    gemm_xg0<<<dim3(MM / 64), dim3(256), 0, stream>>>(x, w0_16, b_ih0, b_hh0, xg);

    lstm_fused<<<dim3(256), dim3(1024), 0, stream>>>(w_hh0, w_ih1, w_hh1,
                                                     b_ih1, b_hh1, xg,
                                                     fc_w, fc_b, out);
}

// Round 13
// 663.762 us; speedup vs baseline: 1.0973x; 1.0973x over previous
//
#include <hip/hip_runtime.h>
#include <hip/hip_fp16.h>

// LSTM B=256,T=512,IN=64,H=128,L=2 + FC.
//  K0 cvt  : w_ih0 -> fp16 (tiny)
//  KG      : xg0 = x(f32).Wih0^T + bias -> [B*T][unit][4g] f16 (fused cvt)
//  KF      : layer-specialized 16-wave recurrence + chunked xg1 GEMM + FC
//
// R13 = R12 + correctly-sized registers. R12 proved the TLP mechanism
// (occupancy 23->46%) but the allocator, with no occupancy hint, sized for
// 8 waves/SIMD (VGPR_Count=64) while LDS caps us at 4 waves/SIMD -> ~55MB
// scratch spill. Fix: __launch_bounds__(1024, 4) + waves_per_eu(4,4) =
// 128-reg/wave budget (the m69 4-waves step). Plus: xg-phase reuses a[] as
// its accumulator (stale-acc: a[g][0] is rewritten each step, [1..3] never
// read -> a is dead at phase entry), shaving peak demand ~16 regs to ~100.
//
// Structure (unchanged from R12): 1024 thr = 16 waves, 1 block/CU. Waves
// 0-7: L0 recurrence + chunk xg-phase; waves 8-15: L1 recurrence one chunk
// behind. Per chunk k (65 chunks, CH=8): 8 steps (1 barrier each):
//   L0-wave (k<NCH): gates0(k*8+j) = h0(j-1) @ Whh0^T + xg0 (prefetched)
//   L1-wave:         gates1((k-1)*8+j) = h1(prev) @ Whh1^T + xg1t[j]
// then xg-phase on L0-waves: xg1t <- h0tile @ Wih1^T + b1 (w1lds 128KB,
// chunk-XOR swizzled) + 1 barrier. k=0: L1 zero-dynamics (zeroed xg1t/h1).
// Broadcast-row MFMA: all 16 A-rows = h; lane holds its unit's gate quad
// in a[g][0]; a[g][1..3] permanently stale.

#define TT 512
#define CH 8
#define NCH 64            // TT / CH
#define MM (256 * 512)
#define HP 136            // padded h0tile row stride

typedef _Float16 f16x4 __attribute__((ext_vector_type(4)));
typedef _Float16 f16x8 __attribute__((ext_vector_type(8)));
typedef float f32x4 __attribute__((ext_vector_type(4)));

__device__ __forceinline__ void bar_lgkm() {
    asm volatile("s_waitcnt lgkmcnt(0)" ::: "memory");
    __builtin_amdgcn_s_barrier();
}

__device__ __forceinline__ float tanh_f(float x) {
    float e = __expf(2.0f * x);
    return 1.0f - 2.0f * __builtin_amdgcn_rcpf(e + 1.0f);
}
__device__ __forceinline__ float sigm_f(float x) {
    return __builtin_amdgcn_rcpf(1.0f + __expf(-x));
}
__device__ __forceinline__ f16x8 cvt8(float4 a, float4 b) {
    f16x8 f;
    f[0] = (_Float16)a.x; f[1] = (_Float16)a.y;
    f[2] = (_Float16)a.z; f[3] = (_Float16)a.w;
    f[4] = (_Float16)b.x; f[5] = (_Float16)b.y;
    f[6] = (_Float16)b.z; f[7] = (_Float16)b.w;
    return f;
}

// ---------------- K0: fp32 -> fp16 cvt (vector4) ----------------
__global__ void cvt_f32_f16(const float* __restrict__ src,
                            _Float16* __restrict__ dst, int n4) {
    int i = blockIdx.x * blockDim.x + threadIdx.x;
    int stride = gridDim.x * blockDim.x;
    for (; i < n4; i += stride) {
        float4 v = ((const float4*)src)[i];
        f16x4 a;
        a[0] = (_Float16)v.x; a[1] = (_Float16)v.y;
        a[2] = (_Float16)v.z; a[3] = (_Float16)v.w;
        ((f16x4*)dst)[i] = a;
    }
}

// ------- KG: xg[M][u][4g] = A32[M,64] . W[512,64]^T + (bih+bhh) ----------
__global__ __launch_bounds__(256, 1) void gemm_xg0(
    const float* __restrict__ A32, const _Float16* __restrict__ W,
    const float* __restrict__ bih, const float* __restrict__ bhh,
    _Float16* __restrict__ out)
{
    const int l  = threadIdx.x & 63;
    const int w  = threadIdx.x >> 6;
    const int mb = blockIdx.x * 64 + w * 16;
    const int c  = l & 15;
    const int q  = l >> 4;

    __shared__ float biasl[512];
    for (int i = threadIdx.x; i < 512; i += 256) biasl[i] = bih[i] + bhh[i];
    __syncthreads();

    f32x4 C[32];
    #pragma unroll
    for (int i = 0; i < 32; ++i) C[i] = (f32x4){0.f, 0.f, 0.f, 0.f};

    #pragma unroll
    for (int ks = 0; ks < 2; ++ks) {
        const float* ap = A32 + (size_t)(mb + c) * 64 + ks * 32 + q * 8;
        f16x8 Af = cvt8(((const float4*)ap)[0], ((const float4*)ap)[1]);
        #pragma unroll
        for (int nt = 0; nt < 32; ++nt) {
            f16x8 Bf = *(const f16x8*)(W + (size_t)(nt * 16 + c) * 64 + ks * 32 + q * 8);
            C[nt] = __builtin_amdgcn_mfma_f32_16x16x32_f16(Af, Bf, C[nt], 0, 0, 0);
        }
    }
    #pragma unroll
    for (int uu = 0; uu < 8; ++uu) {
        float b0 = biasl[uu * 16 + c];
        float b1 = biasl[128 + uu * 16 + c];
        float b2 = biasl[256 + uu * 16 + c];
        float b3 = biasl[384 + uu * 16 + c];
        #pragma unroll
        for (int i = 0; i < 4; ++i) {
            int row = mb + q * 4 + i;
            f16x4 pk;
            pk[0] = (_Float16)(C[uu][i]      + b0);
            pk[1] = (_Float16)(C[8 + uu][i]  + b1);
            pk[2] = (_Float16)(C[16 + uu][i] + b2);
            pk[3] = (_Float16)(C[24 + uu][i] + b3);
            ((f16x4*)out)[(size_t)row * 128 + uu * 16 + c] = pk;
        }
    }
}

// ---------------- KF: 16-wave layer-specialized recurrence ----------------
__global__ __launch_bounds__(1024, 4)
__attribute__((amdgpu_waves_per_eu(4, 4)))
void lstm_fused(
    const float* __restrict__ whh0, const float* __restrict__ wih1,
    const float* __restrict__ whh1,
    const float* __restrict__ bih1, const float* __restrict__ bhh1,
    const _Float16* __restrict__ xg0,   // [B*T][unit][4g] fp16 (bias incl.)
    const float* __restrict__ fc_w, const float* __restrict__ fc_b,
    float* __restrict__ out)
{
    const int t = threadIdx.x;
    const int b = blockIdx.x;
    const int wid = t >> 6;          // 0..15
    const int l = t & 63;
    const int q = l >> 4;            // quad 0..3
    const int c = l & 15;
    const bool isL1 = wid >= 8;
    const int unit = ((wid & 7) << 4) + c;   // 0..127

    __shared__ __align__(16) _Float16 w1lds[512 * 128];   // 128 KB
    __shared__ __align__(16) _Float16 xg1t[CH * 512];     //   8 KB
    __shared__ __align__(16) _Float16 h0tile[CH * HP];    // 2176 B
    __shared__ __align__(16) _Float16 h1buf[2][128];      //  512 B
    __shared__ float redbuf[128];                         //  512 B

    // ---- stage Wih1 -> LDS (half row per thread, cvt + chunk swizzle) ----
    {
        const int r = t >> 1;
        const int jb = (t & 1) << 3;
        const float4* src = (const float4*)(wih1 + (size_t)r * 128);
        #pragma unroll
        for (int j2 = 0; j2 < 8; ++j2) {
            const int j = jb + j2;
            *(f16x8*)&w1lds[r * 128 + ((j ^ (r & 7)) << 3)] =
                cvt8(src[2 * j], src[2 * j + 1]);
        }
    }

    // ---- resident B-frags for THIS wave's layer (64 VGPRs) ----
    const float* whh = isL1 ? whh1 : whh0;
    f16x8 B[4][4];
    #pragma unroll
    for (int g = 0; g < 4; ++g) {
        #pragma unroll
        for (int kt = 0; kt < 4; ++kt) {
            const size_t off = (size_t)((g << 7) + unit) * 128 + (kt << 5) + (q << 3);
            B[g][kt] = cvt8(((const float4*)(whh + off))[0],
                            ((const float4*)(whh + off))[1]);
        }
    }
    // xg-phase bias (L0-waves run the phase)
    float bias1g[4];
    if (!isL1) {
        #pragma unroll
        for (int g = 0; g < 4; ++g)
            bias1g[g] = bih1[(g << 7) + unit] + bhh1[(g << 7) + unit];
    }

    // zeros: xg1t (k=0 L1 zero-dynamics), h1buf both, h0 ring slot CH-1.
    if (t < 512) ((float4*)xg1t)[t] = make_float4(0.f, 0.f, 0.f, 0.f);
    if (t < 128) {
        h1buf[0][t] = (_Float16)0.f;
        h1buf[1][t] = (_Float16)0.f;
        h0tile[(CH - 1) * HP + t] = (_Float16)0.f;
    }

    // xg0 rotating prefetch (L0-waves only; depth 2, compile-time indexed).
    const f16x4* __restrict__ xgp = (const f16x4*)xg0 + (size_t)b * TT * 128 + unit;
    f16x4 xr[4];
    if (!isL1) {
        xr[0] = xgp[0];
        xr[1] = xgp[128];
        xr[2] = xr[0]; xr[3] = xr[0];   // overwritten before first use
    }

    // accumulator; only [0] ever read (stale-lane trick). NOT live across
    // steps (act consumes [0] in-step) -> the xg-phase reuses it freely.
    f32x4 a[4];
    #pragma unroll
    for (int g = 0; g < 4; ++g) a[g] = (f32x4){0.f, 0.f, 0.f, 0.f};
    float cst = 0.f;
    __syncthreads();

    #pragma unroll 1
    for (int k = 0; k <= NCH; ++k) {
        #pragma unroll
        for (int j = 0; j < CH; ++j) {
            const int rp = (j + CH - 1) & (CH - 1);
            if (isL1 || (k < NCH)) {
                // C-in: L0 from prefetched xg0 regs, L1 from xg1t LDS.
                f16x4 xv;
                if (isL1) xv = *(const f16x4*)&xg1t[(j << 9) + (unit << 2)];
                else      xv = xr[j & 3];
                #pragma unroll
                for (int g = 0; g < 4; ++g) a[g][0] = (float)xv[g];
                if (!isL1)   // prefetch step s+2 (spans barriers; ws slack)
                    xr[(j + 2) & 3] = xgp[(size_t)(k * CH + j + 2) * 128];

                // A-frags: broadcast rows of this layer's h (wave-uniform sel)
                const _Float16* hp = isL1 ? &h1buf[(j & 1) ^ 1][0]
                                          : &h0tile[rp * HP];
                #pragma unroll
                for (int kt = 0; kt < 4; ++kt) {
                    f16x8 Af = *(const f16x8*)&hp[(kt << 5) + (q << 3)];
                    #pragma unroll
                    for (int g = 0; g < 4; ++g)
                        a[g] = __builtin_amdgcn_mfma_f32_16x16x32_f16(Af, B[g][kt], a[g], 0, 0, 0);
                }
                // activation (L1 at k=0: exact zero-dynamics, stays 0)
                float gi = sigm_f(a[0][0]);
                float gf = sigm_f(a[1][0]);
                float gg = tanh_f(a[2][0]);
                float go = sigm_f(a[3][0]);
                cst = gf * cst + gi * gg;
                float hh = go * tanh_f(cst);
                if (l < 16) {
                    _Float16* wp = isL1 ? &h1buf[j & 1][unit]
                                        : &h0tile[j * HP + unit];
                    *wp = (_Float16)hh;
                    if (isL1 && k == NCH && j == CH - 1) redbuf[unit] = hh;
                }
            }
            bar_lgkm();   // h0(j)/h1(j) visible; vm loads stay in flight
        }

        // ---- xg-phase (L0-waves): xg1t = h0tile(chunk k) @ Wih1^T + b1 ----
        // Reuses a[] as accumulator (dead at phase entry; next step rewrites
        // a[g][0] before any read, [1..3] are never read).
        if (k < NCH) {
            if (!isL1) {
                #pragma unroll
                for (int g = 0; g < 4; ++g)
                    a[g] = (f32x4){bias1g[g], bias1g[g], bias1g[g], bias1g[g]};
                #pragma unroll
                for (int kt = 0; kt < 4; ++kt) {
                    f16x8 Ah = *(const f16x8*)&h0tile[(c & 7) * HP + (kt << 5) + (q << 3)];
                    #pragma unroll
                    for (int g = 0; g < 4; ++g) {
                        f16x8 Bg = *(const f16x8*)&w1lds[(((g << 7) + unit) << 7) +
                                       ((((kt << 2) + q) ^ (c & 7)) << 3)];
                        a[g] = __builtin_amdgcn_mfma_f32_16x16x32_f16(Ah, Bg, a[g], 0, 0, 0);
                    }
                }
                #pragma unroll
                for (int i2 = 0; i2 < 4; ++i2) {   // D rows 8..15 dup rows 0..7
                    f16x4 pk;
                    pk[0] = (_Float16)a[0][i2]; pk[1] = (_Float16)a[1][i2];
                    pk[2] = (_Float16)a[2][i2]; pk[3] = (_Float16)a[3][i2];
                    *(f16x4*)&xg1t[((((q << 2) + i2) & 7) << 9) + (unit << 2)] = pk;
                }
            }
            bar_lgkm();
        }
    }

    // fused FC on h1(T-1) (redbuf written before the last in-loop barrier)
    if (t < 64) {
        float p = redbuf[t] * fc_w[t] + redbuf[t + 64] * fc_w[t + 64];
        #pragma unroll
        for (int off = 32; off > 0; off >>= 1) p += __shfl_down(p, off, 64);
        if (t == 0) out[b] = p + fc_b[0];
    }
}

extern "C" void kernel_launch(void* const* d_in, const int* in_sizes, int n_in,
                              void* d_out, int out_size, void* d_ws, size_t ws_size,
                              hipStream_t stream) {
    const float* x     = (const float*)d_in[0];
    const float* w_ih0 = (const float*)d_in[1];
    const float* w_hh0 = (const float*)d_in[2];
    const float* b_ih0 = (const float*)d_in[3];
    const float* b_hh0 = (const float*)d_in[4];
    const float* w_ih1 = (const float*)d_in[5];
    const float* w_hh1 = (const float*)d_in[6];
    const float* b_ih1 = (const float*)d_in[7];
    const float* b_hh1 = (const float*)d_in[8];
    const float* fc_w  = (const float*)d_in[9];
    const float* fc_b  = (const float*)d_in[10];
    float* out = (float*)d_out;

    // ws layout: xg [134217728] + 64KB prefetch slack + w0_16 [65536]
    char* ws = (char*)d_ws;
    _Float16* xg    = (_Float16*)(ws);
    _Float16* w0_16 = (_Float16*)(ws + 134217728 + 65536);

    cvt_f32_f16<<<dim3(32), dim3(256), 0, stream>>>(w_ih0, w0_16, (512 * 64) / 4);

    gemm_xg0<<<dim3(MM / 64), dim3(256), 0, stream>>>(x, w0_16, b_ih0, b_hh0, xg);

    lstm_fused<<<dim3(256), dim3(1024), 0, stream>>>(w_hh0, w_ih1, w_hh1,
                                                     b_ih1, b_hh1, xg,
                                                     fc_w, fc_b, out);
}